// Round 1
// baseline (258.405 us; speedup 1.0000x reference)
//
#include <hip/hip_runtime.h>
#include <hip/hip_bf16.h>

constexpr int BB = 32;     // batches
constexpr int P  = 1024;   // patches per batch
constexpr int O  = 128;    // objects per batch
constexpr int D  = 512;    // feature dim
constexpr int PT = 128;    // patch rows per block
constexpr int BK = 64;     // K-step
constexpr float EPS = 1e-8f;
constexpr float SCL = 14.426950408889634f; // (1/0.1) * log2(e)

typedef __attribute__((ext_vector_type(8))) short short8;
typedef __attribute__((ext_vector_type(16))) float f32x16;

__device__ __forceinline__ unsigned short f2bf(float f) {
  __hip_bfloat16 h = __float2bfloat16(f);
  unsigned short u;
  __builtin_memcpy(&u, &h, sizeof(u));
  return u;
}

// one wave per row: inv_norm = 1 / max(||x||, 1e-12)
__global__ __launch_bounds__(256) void norm_kernel(
    const float* __restrict__ pf, const float* __restrict__ of,
    float* __restrict__ invp, float* __restrict__ invo) {
  int lane = threadIdx.x & 63;
  int row = blockIdx.x * 4 + (threadIdx.x >> 6);
  const float* src;
  float* dst;
  if (row < BB * P) {
    src = pf + (size_t)row * D;
    dst = invp + row;
  } else {
    int r = row - BB * P;
    if (r >= BB * O) return;
    src = of + (size_t)r * D;
    dst = invo + r;
  }
  float ss = 0.f;
  #pragma unroll
  for (int i = 0; i < 2; ++i) {
    float4 v = *(const float4*)(src + (lane + 64 * i) * 4);
    ss += v.x * v.x + v.y * v.y + v.z * v.z + v.w * v.w;
  }
  #pragma unroll
  for (int s = 1; s < 64; s <<= 1) ss += __shfl_xor(ss, s);
  if (lane == 0) *dst = 1.0f / fmaxf(sqrtf(ss), 1e-12f);
}

__global__ __launch_bounds__(256) void icl_main(
    const float* __restrict__ pf, const float* __restrict__ of,
    const float* __restrict__ e1i, const float* __restrict__ e1j,
    const float* __restrict__ e2j, const float* __restrict__ invp,
    const float* __restrict__ invo, float* __restrict__ accum) {

  // XOR-swizzled bf16 tiles: elem offset = row*BK + ((chunk16 ^ (row&7))<<3) + sub
  __shared__ __hip_bfloat16 As[PT * BK];
  __shared__ __hip_bfloat16 Bs[PT * BK];
  __shared__ float d_l[2][PT], s2_l[2][PT], ei_l[2][PT], s1_l[2][PT], mv_l[2][PT];
  __shared__ int   mi_l[2][PT];
  __shared__ float red[12];

  const int tid  = threadIdx.x;
  const int lane = tid & 63;
  const int wid  = tid >> 6;
  const int wr   = wid >> 1;   // wave row-group (2)
  const int wc   = wid & 1;    // wave col-group (2)
  const int half = lane >> 5;
  const int l31  = lane & 31;

  // XCD grouping: all 8 row-tiles of batch b share blockIdx%8 -> same XCD L2
  const int b    = blockIdx.x & 31;
  const int pt   = blockIdx.x >> 5;
  const int row0 = pt * PT;

  const float* pfb = pf + (size_t)b * P * D;
  const float* ofb = of + (size_t)b * O * D;
  const float* ivp = invp + b * P + row0;  // this block's A rows
  const float* ivq = invp + b * P;         // patch rows as B panels
  const float* ivo = invo + b * O;

  float s1p[2][16];
  #pragma unroll
  for (int m = 0; m < 2; ++m)
    #pragma unroll
    for (int r = 0; r < 16; ++r) s1p[m][r] = 0.f;

  auto stage = [&](const float* __restrict__ src, const float* __restrict__ inv,
                   __hip_bfloat16* __restrict__ lds, int k0) {
    #pragma unroll
    for (int i = 0; i < 8; ++i) {
      int c = i * 256 + tid;      // 2048 chunks of float4
      int rr = c >> 4, kc = c & 15;
      float4 v = *(const float4*)(src + (size_t)rr * D + k0 + (kc << 2));
      float s = inv[rr];
      int off = rr * BK + ((((kc >> 1) ^ (rr & 7)) << 3) | ((kc & 1) << 2));
      ushort4 w;
      w.x = f2bf(v.x * s);
      w.y = f2bf(v.y * s);
      w.z = f2bf(v.z * s);
      w.w = f2bf(v.w * s);
      *reinterpret_cast<ushort4*>(lds + off) = w;
    }
  };

  for (int ct = 0; ct < 9; ++ct) {
    const float* bsrc = (ct == 0) ? ofb : pfb + (size_t)(ct - 1) * 128 * D;
    const float* binv = (ct == 0) ? ivo : ivq + (ct - 1) * 128;

    f32x16 acc[2][2];
    #pragma unroll
    for (int m = 0; m < 2; ++m)
      #pragma unroll
      for (int n = 0; n < 2; ++n)
        #pragma unroll
        for (int k = 0; k < 16; ++k) acc[m][n][k] = 0.f;

    for (int ks = 0; ks < D / BK; ++ks) {
      __syncthreads();  // previous tile's reads done before overwrite
      stage(pfb + (size_t)row0 * D, ivp, As, ks * BK);
      stage(bsrc, binv, Bs, ks * BK);
      __syncthreads();
      #pragma unroll
      for (int kc = 0; kc < 4; ++kc) {
        short8 af[2], bfr[2];
        #pragma unroll
        for (int m = 0; m < 2; ++m) {
          int row = wr * 64 + m * 32 + l31;
          af[m] = *reinterpret_cast<const short8*>(
              As + row * BK + ((((kc << 1) | half) ^ (row & 7)) << 3));
        }
        #pragma unroll
        for (int n = 0; n < 2; ++n) {
          int col = wc * 64 + n * 32 + l31;
          bfr[n] = *reinterpret_cast<const short8*>(
              Bs + col * BK + ((((kc << 1) | half) ^ (col & 7)) << 3));
        }
        #pragma unroll
        for (int m = 0; m < 2; ++m)
          #pragma unroll
          for (int n = 0; n < 2; ++n)
            acc[m][n] = __builtin_amdgcn_mfma_f32_32x32x16_bf16(
                af[m], bfr[n], acc[m][n], 0, 0, 0);
      }
    }

    if (ct == 0) {
      // objects tile: delta (e1i*po_exp), s2 (e2j*po_exp), e1i row-sum, argmax
      #pragma unroll
      for (int m = 0; m < 2; ++m) {
        #pragma unroll
        for (int r = 0; r < 16; ++r) {
          int lrow = wr * 64 + m * 32 + (r & 3) + ((r >> 2) << 3) + (half << 2);
          size_t base = ((size_t)b * P + row0 + lrow) * O;
          float dsum = 0.f, s2s = 0.f, eis = 0.f, mval = -1e30f;
          int midx = 0;
          #pragma unroll
          for (int n = 0; n < 2; ++n) {
            int col = wc * 64 + n * 32 + l31;
            float sim = acc[m][n][r];
            float e = exp2f(sim * SCL);
            float v1 = e1i[base + col];
            float v2 = e2j[base + col];
            dsum += v1 * e;
            s2s  += v2 * e;
            eis  += v1;
            if (sim > mval) { mval = sim; midx = col; }
          }
          #pragma unroll
          for (int s = 1; s < 32; s <<= 1) {
            dsum += __shfl_xor(dsum, s);
            s2s  += __shfl_xor(s2s, s);
            eis  += __shfl_xor(eis, s);
            float ov = __shfl_xor(mval, s);
            int   oi = __shfl_xor(midx, s);
            if (ov > mval || (ov == mval && oi < midx)) { mval = ov; midx = oi; }
          }
          if (l31 == 0) {
            d_l[wc][lrow] = dsum;
            s2_l[wc][lrow] = s2s;
            ei_l[wc][lrow] = eis;
            mv_l[wc][lrow] = mval;
            mi_l[wc][lrow] = midx;
          }
        }
      }
    } else {
      // patch tile: s1 += e1j * pp_exp, accumulated in registers across tiles
      const int qbase = (ct - 1) * 128;
      #pragma unroll
      for (int m = 0; m < 2; ++m) {
        #pragma unroll
        for (int r = 0; r < 16; ++r) {
          int lrow = wr * 64 + m * 32 + (r & 3) + ((r >> 2) << 3) + (half << 2);
          size_t base = ((size_t)b * P + row0 + lrow) * P + qbase;
          float s = 0.f;
          #pragma unroll
          for (int n = 0; n < 2; ++n) {
            int col = wc * 64 + n * 32 + l31;
            s += e1j[base + col] * exp2f(acc[m][n][r] * SCL);
          }
          s1p[m][r] += s;
        }
      }
    }
  }

  // reduce s1 register partials across lanes -> LDS
  #pragma unroll
  for (int m = 0; m < 2; ++m) {
    #pragma unroll
    for (int r = 0; r < 16; ++r) {
      float v = s1p[m][r];
      #pragma unroll
      for (int s = 1; s < 32; s <<= 1) v += __shfl_xor(v, s);
      if (l31 == 0) {
        int lrow = wr * 64 + m * 32 + (r & 3) + ((r >> 2) << 3) + (half << 2);
        s1_l[wc][lrow] = v;
      }
    }
  }
  __syncthreads();

  // per-row loss + label, then block reduce
  float lsum = 0.f, lbl = 0.f, vct = 0.f;
  if (tid < PT) {
    float delta = d_l[0][tid] + d_l[1][tid];
    float s2 = s2_l[0][tid] + s2_l[1][tid];
    float eis = ei_l[0][tid] + ei_l[1][tid];
    float s1 = s1_l[0][tid] + s1_l[1][tid];
    float m0 = mv_l[0][tid], m1 = mv_l[1][tid];
    int mi = (m1 > m0) ? mi_l[1][tid] : mi_l[0][tid];  // tie -> lower col (slot 0)
    float valid = (eis > 0.f) ? 1.f : 0.f;
    float ratio = delta / (delta + s1 + s2 + EPS);
    float loss = -logf(ratio + EPS);
    float label = e1i[((size_t)b * P + row0 + tid) * O + mi];
    lsum = loss * valid;
    lbl  = label * valid;
    vct  = valid;
  }
  #pragma unroll
  for (int s = 1; s < 64; s <<= 1) {
    lsum += __shfl_xor(lsum, s);
    lbl  += __shfl_xor(lbl, s);
    vct  += __shfl_xor(vct, s);
  }
  if (lane == 0) {
    red[wid * 3 + 0] = lsum;
    red[wid * 3 + 1] = lbl;
    red[wid * 3 + 2] = vct;
  }
  __syncthreads();
  if (tid == 0) {
    float a = red[0] + red[3] + red[6] + red[9];
    float c = red[1] + red[4] + red[7] + red[10];
    float v = red[2] + red[5] + red[8] + red[11];
    atomicAdd(&accum[0], a);
    atomicAdd(&accum[1], c);
    atomicAdd(&accum[2], v);
  }
}

__global__ void finalize_kernel(const float* __restrict__ accum,
                                float* __restrict__ out) {
  if (threadIdx.x == 0 && blockIdx.x == 0) {
    float nv = accum[2];
    out[0] = accum[0] / nv;
    out[1] = accum[1] / nv;
  }
}

extern "C" void kernel_launch(void* const* d_in, const int* in_sizes, int n_in,
                              void* d_out, int out_size, void* d_ws, size_t ws_size,
                              hipStream_t stream) {
  const float* pf  = (const float*)d_in[0];
  const float* of  = (const float*)d_in[1];
  const float* e1i = (const float*)d_in[2];
  const float* e1j = (const float*)d_in[3];
  const float* e2j = (const float*)d_in[4];

  float* ws    = (float*)d_ws;
  float* accum = ws;                 // [0]=loss_sum [1]=label_sum [2]=valid_sum
  float* invp  = ws + 16;            // BB*P floats
  float* invo  = ws + 16 + BB * P;   // BB*O floats

  hipMemsetAsync(accum, 0, 16 * sizeof(float), stream);
  norm_kernel<<<(BB * P + BB * O) / 4, 256, 0, stream>>>(pf, of, invp, invo);
  icl_main<<<BB * (P / PT), 256, 0, stream>>>(pf, of, e1i, e1j, e2j, invp, invo, accum);
  finalize_kernel<<<1, 64, 0, stream>>>(accum, (float*)d_out);
}

// Round 2
// 199.355 us; speedup vs baseline: 1.2962x; 1.2962x over previous
//
#include <hip/hip_runtime.h>
#include <hip/hip_bf16.h>

constexpr int BB = 32;     // batches
constexpr int P  = 1024;   // patches per batch
constexpr int O  = 128;    // objects per batch
constexpr int D  = 512;    // feature dim
constexpr float EPS = 1e-8f;
constexpr float SCL = 14.426950408889634f; // (1/0.1) * log2(e)

typedef __attribute__((ext_vector_type(8))) short short8;
typedef __attribute__((ext_vector_type(16))) float f32x16;

__device__ __forceinline__ unsigned short f2bf(float f) {
  __hip_bfloat16 h = __float2bfloat16(f);
  unsigned short u;
  __builtin_memcpy(&u, &h, sizeof(u));
  return u;
}

__device__ __forceinline__ void gld_lds16(const void* g, void* l) {
  __builtin_amdgcn_global_load_lds(
      (const __attribute__((address_space(1))) void*)g,
      (__attribute__((address_space(3))) void*)l, 16, 0, 0);
}

// ---------------- prep: normalized bf16 features into workspace ------------
__global__ __launch_bounds__(256) void prep_kernel(
    const float* __restrict__ pf, const float* __restrict__ of,
    __hip_bfloat16* __restrict__ pn, __hip_bfloat16* __restrict__ on) {
  int lane = threadIdx.x & 63;
  int row = blockIdx.x * 4 + (threadIdx.x >> 6);
  const float* src;
  __hip_bfloat16* dst;
  if (row < BB * P) {
    src = pf + (size_t)row * D;
    dst = pn + (size_t)row * D;
  } else {
    int r = row - BB * P;
    if (r >= BB * O) return;
    src = of + (size_t)r * D;
    dst = on + (size_t)r * D;
  }
  float4 v0 = *(const float4*)(src + lane * 8);
  float4 v1 = *(const float4*)(src + lane * 8 + 4);
  float ss = v0.x * v0.x + v0.y * v0.y + v0.z * v0.z + v0.w * v0.w +
             v1.x * v1.x + v1.y * v1.y + v1.z * v1.z + v1.w * v1.w;
  #pragma unroll
  for (int s = 1; s < 64; s <<= 1) ss += __shfl_xor(ss, s);
  float sc = 1.0f / fmaxf(sqrtf(ss), 1e-12f);
  short8 w;
  w[0] = (short)f2bf(v0.x * sc); w[1] = (short)f2bf(v0.y * sc);
  w[2] = (short)f2bf(v0.z * sc); w[3] = (short)f2bf(v0.w * sc);
  w[4] = (short)f2bf(v1.x * sc); w[5] = (short)f2bf(v1.y * sc);
  w[6] = (short)f2bf(v1.z * sc); w[7] = (short)f2bf(v1.w * sc);
  *reinterpret_cast<short8*>(dst + lane * 8) = w;
}

// ---------------- main v2: PT=64, grid 512 (2 blocks/CU), gload_lds --------
__global__ __launch_bounds__(256) void icl_main2(
    const __hip_bfloat16* __restrict__ pn, const __hip_bfloat16* __restrict__ on,
    const float* __restrict__ e1i, const float* __restrict__ e1j,
    const float* __restrict__ e2j, float* __restrict__ accum) {

  // XOR-swizzled bf16 tiles; 16B chunk c of row r lives at chunk (c ^ (r&7))
  __shared__ __hip_bfloat16 As[64 * 64];    // 8 KB
  __shared__ __hip_bfloat16 Bs[128 * 64];   // 16 KB
  __shared__ float Ms[64 * 128];            // 32 KB mask tile (linear)
  __shared__ float d_l[2][64], s2_l[2][64], ei_l[2][64], s1_l[2][64], mv_l[2][64];
  __shared__ int   mi_l[2][64];

  const int tid  = threadIdx.x;
  const int lane = tid & 63;
  const int wid  = tid >> 6;
  const int wr   = wid >> 1;   // wave row-group (2): rows wr*32..+31
  const int wc   = wid & 1;    // wave col-group (2): cols wc*64..+63
  const int half = lane >> 5;
  const int l31  = lane & 31;

  const int b    = blockIdx.x & 31;
  const int pt   = blockIdx.x >> 5;   // 16 row-tiles
  const int row0 = pt * 64;

  const __hip_bfloat16* pnb  = pn + (size_t)b * P * D;
  const __hip_bfloat16* onb  = on + (size_t)b * O * D;
  const __hip_bfloat16* arow = pnb + (size_t)row0 * D;

  float s1p[16];
  #pragma unroll
  for (int r = 0; r < 16; ++r) s1p[r] = 0.f;

  for (int ct = 0; ct < 9; ++ct) {
    const __hip_bfloat16* bsrc = (ct == 0) ? onb : pnb + (size_t)(ct - 1) * 128 * D;

    // ---- mask prefetch into Ms (drained by the ks=0 barrier, i.e. free) ----
    {
      const float* msrc;
      size_t rstride;
      if (ct == 0) { msrc = e2j + ((size_t)b * P + row0) * O; rstride = O; }
      else         { msrc = e1j + ((size_t)b * P + row0) * P + (ct - 1) * 128; rstride = P; }
      #pragma unroll
      for (int i = 0; i < 8; ++i) {
        int q = i * 256 + tid;          // 2048 16B chunks
        int rr = q >> 5, cc = q & 31;   // 32 chunks per 128-col row
        gld_lds16(msrc + (size_t)rr * rstride + (cc << 2),
                  (char*)Ms + (size_t)(i * 256 + wid * 64) * 16);
      }
    }

    f32x16 acc[2];
    #pragma unroll
    for (int n = 0; n < 2; ++n)
      #pragma unroll
      for (int k = 0; k < 16; ++k) acc[n][k] = 0.f;

    for (int ks = 0; ks < D / 64; ++ks) {
      const int k0 = ks * 64;
      // stage A tile 64x64 (512 chunks, 2 insts), pre-swizzled source
      #pragma unroll
      for (int i = 0; i < 2; ++i) {
        int q = i * 256 + tid;
        int rr = q >> 3, c = q & 7;
        int gc = c ^ (rr & 7);
        gld_lds16(arow + (size_t)rr * D + k0 + gc * 8,
                  (char*)As + (size_t)(i * 256 + wid * 64) * 16);
      }
      // stage B tile 128x64 (1024 chunks, 4 insts)
      #pragma unroll
      for (int i = 0; i < 4; ++i) {
        int q = i * 256 + tid;
        int rr = q >> 3, c = q & 7;
        int gc = c ^ (rr & 7);
        gld_lds16(bsrc + (size_t)rr * D + k0 + gc * 8,
                  (char*)Bs + (size_t)(i * 256 + wid * 64) * 16);
      }
      __syncthreads();   // vmcnt(0) drain: As/Bs (and Ms on ks==0) ready
      #pragma unroll
      for (int kc = 0; kc < 4; ++kc) {
        int row = wr * 32 + l31;
        short8 af = *reinterpret_cast<const short8*>(
            As + row * 64 + ((((kc << 1) | half) ^ (row & 7)) << 3));
        short8 bfr[2];
        #pragma unroll
        for (int n = 0; n < 2; ++n) {
          int col = wc * 64 + n * 32 + l31;
          bfr[n] = *reinterpret_cast<const short8*>(
              Bs + col * 64 + ((((kc << 1) | half) ^ (col & 7)) << 3));
        }
        #pragma unroll
        for (int n = 0; n < 2; ++n)
          acc[n] = __builtin_amdgcn_mfma_f32_32x32x16_bf16(af, bfr[n], acc[n], 0, 0, 0);
      }
      __syncthreads();   // LDS reads done before next stage overwrites
    }

    if (ct == 0) {
      // objects tile: delta (e1i), s2 (e2j from LDS), e1i row-sum, argmax
      #pragma unroll
      for (int r = 0; r < 16; ++r) {
        int lrow = wr * 32 + (r & 3) + ((r >> 2) << 3) + (half << 2);
        size_t gbase = ((size_t)b * P + row0 + lrow) * O;
        float dsum = 0.f, s2s = 0.f, eis = 0.f, mval = -1e30f;
        int midx = 0;
        #pragma unroll
        for (int n = 0; n < 2; ++n) {
          int col = wc * 64 + n * 32 + l31;
          float sim = acc[n][r];
          float e = exp2f(sim * SCL);
          float v1 = e1i[gbase + col];
          float v2 = Ms[lrow * 128 + col];
          dsum += v1 * e;
          s2s  += v2 * e;
          eis  += v1;
          if (sim > mval) { mval = sim; midx = col; }
        }
        #pragma unroll
        for (int s = 1; s < 32; s <<= 1) {
          dsum += __shfl_xor(dsum, s);
          s2s  += __shfl_xor(s2s, s);
          eis  += __shfl_xor(eis, s);
          float ov = __shfl_xor(mval, s);
          int   oi = __shfl_xor(midx, s);
          if (ov > mval || (ov == mval && oi < midx)) { mval = ov; midx = oi; }
        }
        if (l31 == 0) {
          d_l[wc][lrow] = dsum;
          s2_l[wc][lrow] = s2s;
          ei_l[wc][lrow] = eis;
          mv_l[wc][lrow] = mval;
          mi_l[wc][lrow] = midx;
        }
      }
    } else {
      // patch tile: s1 += e1j (LDS) * pp_exp, accumulated in registers
      #pragma unroll
      for (int r = 0; r < 16; ++r) {
        int lrow = wr * 32 + (r & 3) + ((r >> 2) << 3) + (half << 2);
        float s = 0.f;
        #pragma unroll
        for (int n = 0; n < 2; ++n) {
          int col = wc * 64 + n * 32 + l31;
          s += Ms[lrow * 128 + col] * exp2f(acc[n][r] * SCL);
        }
        s1p[r] += s;
      }
    }
    __syncthreads();   // epilogue reads of Ms done before next prefetch
  }

  // reduce s1 partials across lanes -> LDS
  #pragma unroll
  for (int r = 0; r < 16; ++r) {
    float v = s1p[r];
    #pragma unroll
    for (int s = 1; s < 32; s <<= 1) v += __shfl_xor(v, s);
    if (l31 == 0) {
      int lrow = wr * 32 + (r & 3) + ((r >> 2) << 3) + (half << 2);
      s1_l[wc][lrow] = v;
    }
  }
  __syncthreads();

  // per-row loss + label; only wave 0 participates
  if (tid < 64) {
    float delta = d_l[0][tid] + d_l[1][tid];
    float s2 = s2_l[0][tid] + s2_l[1][tid];
    float eis = ei_l[0][tid] + ei_l[1][tid];
    float s1 = s1_l[0][tid] + s1_l[1][tid];
    float m0 = mv_l[0][tid], m1 = mv_l[1][tid];
    int mi = (m1 > m0) ? mi_l[1][tid] : mi_l[0][tid];  // tie -> lower col
    float valid = (eis > 0.f) ? 1.f : 0.f;
    float ratio = delta / (delta + s1 + s2 + EPS);
    float loss = -logf(ratio + EPS);
    float label = e1i[((size_t)b * P + row0 + tid) * O + mi];
    float lsum = loss * valid;
    float lbl  = label * valid;
    float vct  = valid;
    #pragma unroll
    for (int s = 1; s < 64; s <<= 1) {
      lsum += __shfl_xor(lsum, s);
      lbl  += __shfl_xor(lbl, s);
      vct  += __shfl_xor(vct, s);
    }
    if (tid == 0) {
      atomicAdd(&accum[0], lsum);
      atomicAdd(&accum[1], lbl);
      atomicAdd(&accum[2], vct);
    }
  }
}

// ---------------- fallback path (round-1, known correct) -------------------
__global__ __launch_bounds__(256) void norm_kernel(
    const float* __restrict__ pf, const float* __restrict__ of,
    float* __restrict__ invp, float* __restrict__ invo) {
  int lane = threadIdx.x & 63;
  int row = blockIdx.x * 4 + (threadIdx.x >> 6);
  const float* src;
  float* dst;
  if (row < BB * P) {
    src = pf + (size_t)row * D;
    dst = invp + row;
  } else {
    int r = row - BB * P;
    if (r >= BB * O) return;
    src = of + (size_t)r * D;
    dst = invo + r;
  }
  float ss = 0.f;
  #pragma unroll
  for (int i = 0; i < 2; ++i) {
    float4 v = *(const float4*)(src + (lane + 64 * i) * 4);
    ss += v.x * v.x + v.y * v.y + v.z * v.z + v.w * v.w;
  }
  #pragma unroll
  for (int s = 1; s < 64; s <<= 1) ss += __shfl_xor(ss, s);
  if (lane == 0) *dst = 1.0f / fmaxf(sqrtf(ss), 1e-12f);
}

__global__ __launch_bounds__(256) void icl_main_v1(
    const float* __restrict__ pf, const float* __restrict__ of,
    const float* __restrict__ e1i, const float* __restrict__ e1j,
    const float* __restrict__ e2j, const float* __restrict__ invp,
    const float* __restrict__ invo, float* __restrict__ accum) {
  constexpr int PT = 128, BK = 64;
  __shared__ __hip_bfloat16 As[PT * BK];
  __shared__ __hip_bfloat16 Bs[PT * BK];
  __shared__ float d_l[2][PT], s2_l[2][PT], ei_l[2][PT], s1_l[2][PT], mv_l[2][PT];
  __shared__ int   mi_l[2][PT];
  __shared__ float red[12];

  const int tid  = threadIdx.x;
  const int lane = tid & 63;
  const int wid  = tid >> 6;
  const int wr   = wid >> 1;
  const int wc   = wid & 1;
  const int half = lane >> 5;
  const int l31  = lane & 31;
  const int b    = blockIdx.x & 31;
  const int pt   = blockIdx.x >> 5;
  const int row0 = pt * PT;

  const float* pfb = pf + (size_t)b * P * D;
  const float* ofb = of + (size_t)b * O * D;
  const float* ivp = invp + b * P + row0;
  const float* ivq = invp + b * P;
  const float* ivo = invo + b * O;

  float s1p[2][16];
  #pragma unroll
  for (int m = 0; m < 2; ++m)
    #pragma unroll
    for (int r = 0; r < 16; ++r) s1p[m][r] = 0.f;

  auto stage = [&](const float* __restrict__ src, const float* __restrict__ inv,
                   __hip_bfloat16* __restrict__ lds, int k0) {
    #pragma unroll
    for (int i = 0; i < 8; ++i) {
      int c = i * 256 + tid;
      int rr = c >> 4, kc = c & 15;
      float4 v = *(const float4*)(src + (size_t)rr * D + k0 + (kc << 2));
      float s = inv[rr];
      int off = rr * BK + ((((kc >> 1) ^ (rr & 7)) << 3) | ((kc & 1) << 2));
      ushort4 w;
      w.x = f2bf(v.x * s);
      w.y = f2bf(v.y * s);
      w.z = f2bf(v.z * s);
      w.w = f2bf(v.w * s);
      *reinterpret_cast<ushort4*>(lds + off) = w;
    }
  };

  for (int ct = 0; ct < 9; ++ct) {
    const float* bsrc = (ct == 0) ? ofb : pfb + (size_t)(ct - 1) * 128 * D;
    const float* binv = (ct == 0) ? ivo : ivq + (ct - 1) * 128;

    f32x16 acc[2][2];
    #pragma unroll
    for (int m = 0; m < 2; ++m)
      #pragma unroll
      for (int n = 0; n < 2; ++n)
        #pragma unroll
        for (int k = 0; k < 16; ++k) acc[m][n][k] = 0.f;

    for (int ks = 0; ks < D / BK; ++ks) {
      __syncthreads();
      stage(pfb + (size_t)row0 * D, ivp, As, ks * BK);
      stage(bsrc, binv, Bs, ks * BK);
      __syncthreads();
      #pragma unroll
      for (int kc = 0; kc < 4; ++kc) {
        short8 af[2], bfr[2];
        #pragma unroll
        for (int m = 0; m < 2; ++m) {
          int row = wr * 64 + m * 32 + l31;
          af[m] = *reinterpret_cast<const short8*>(
              As + row * BK + ((((kc << 1) | half) ^ (row & 7)) << 3));
        }
        #pragma unroll
        for (int n = 0; n < 2; ++n) {
          int col = wc * 64 + n * 32 + l31;
          bfr[n] = *reinterpret_cast<const short8*>(
              Bs + col * BK + ((((kc << 1) | half) ^ (col & 7)) << 3));
        }
        #pragma unroll
        for (int m = 0; m < 2; ++m)
          #pragma unroll
          for (int n = 0; n < 2; ++n)
            acc[m][n] = __builtin_amdgcn_mfma_f32_32x32x16_bf16(
                af[m], bfr[n], acc[m][n], 0, 0, 0);
      }
    }

    if (ct == 0) {
      #pragma unroll
      for (int m = 0; m < 2; ++m) {
        #pragma unroll
        for (int r = 0; r < 16; ++r) {
          int lrow = wr * 64 + m * 32 + (r & 3) + ((r >> 2) << 3) + (half << 2);
          size_t base = ((size_t)b * P + row0 + lrow) * O;
          float dsum = 0.f, s2s = 0.f, eis = 0.f, mval = -1e30f;
          int midx = 0;
          #pragma unroll
          for (int n = 0; n < 2; ++n) {
            int col = wc * 64 + n * 32 + l31;
            float sim = acc[m][n][r];
            float e = exp2f(sim * SCL);
            float v1 = e1i[base + col];
            float v2 = e2j[base + col];
            dsum += v1 * e;
            s2s  += v2 * e;
            eis  += v1;
            if (sim > mval) { mval = sim; midx = col; }
          }
          #pragma unroll
          for (int s = 1; s < 32; s <<= 1) {
            dsum += __shfl_xor(dsum, s);
            s2s  += __shfl_xor(s2s, s);
            eis  += __shfl_xor(eis, s);
            float ov = __shfl_xor(mval, s);
            int   oi = __shfl_xor(midx, s);
            if (ov > mval || (ov == mval && oi < midx)) { mval = ov; midx = oi; }
          }
          if (l31 == 0) {
            d_l[wc][lrow] = dsum;
            s2_l[wc][lrow] = s2s;
            ei_l[wc][lrow] = eis;
            mv_l[wc][lrow] = mval;
            mi_l[wc][lrow] = midx;
          }
        }
      }
    } else {
      const int qbase = (ct - 1) * 128;
      #pragma unroll
      for (int m = 0; m < 2; ++m) {
        #pragma unroll
        for (int r = 0; r < 16; ++r) {
          int lrow = wr * 64 + m * 32 + (r & 3) + ((r >> 2) << 3) + (half << 2);
          size_t base = ((size_t)b * P + row0 + lrow) * P + qbase;
          float s = 0.f;
          #pragma unroll
          for (int n = 0; n < 2; ++n) {
            int col = wc * 64 + n * 32 + l31;
            s += e1j[base + col] * exp2f(acc[m][n][r] * SCL);
          }
          s1p[m][r] += s;
        }
      }
    }
  }

  #pragma unroll
  for (int m = 0; m < 2; ++m) {
    #pragma unroll
    for (int r = 0; r < 16; ++r) {
      float v = s1p[m][r];
      #pragma unroll
      for (int s = 1; s < 32; s <<= 1) v += __shfl_xor(v, s);
      if (l31 == 0) {
        int lrow = wr * 64 + m * 32 + (r & 3) + ((r >> 2) << 3) + (half << 2);
        s1_l[wc][lrow] = v;
      }
    }
  }
  __syncthreads();

  float lsum = 0.f, lbl = 0.f, vct = 0.f;
  if (tid < PT) {
    float delta = d_l[0][tid] + d_l[1][tid];
    float s2 = s2_l[0][tid] + s2_l[1][tid];
    float eis = ei_l[0][tid] + ei_l[1][tid];
    float s1 = s1_l[0][tid] + s1_l[1][tid];
    float m0 = mv_l[0][tid], m1 = mv_l[1][tid];
    int mi = (m1 > m0) ? mi_l[1][tid] : mi_l[0][tid];
    float valid = (eis > 0.f) ? 1.f : 0.f;
    float ratio = delta / (delta + s1 + s2 + EPS);
    float loss = -logf(ratio + EPS);
    float label = e1i[((size_t)b * P + row0 + tid) * O + mi];
    lsum = loss * valid;
    lbl  = label * valid;
    vct  = valid;
  }
  #pragma unroll
  for (int s = 1; s < 64; s <<= 1) {
    lsum += __shfl_xor(lsum, s);
    lbl  += __shfl_xor(lbl, s);
    vct  += __shfl_xor(vct, s);
  }
  if (lane == 0) {
    red[wid * 3 + 0] = lsum;
    red[wid * 3 + 1] = lbl;
    red[wid * 3 + 2] = vct;
  }
  __syncthreads();
  if (tid == 0) {
    float a = red[0] + red[3] + red[6] + red[9];
    float c = red[1] + red[4] + red[7] + red[10];
    float v = red[2] + red[5] + red[8] + red[11];
    atomicAdd(&accum[0], a);
    atomicAdd(&accum[1], c);
    atomicAdd(&accum[2], v);
  }
}

__global__ void finalize_kernel(const float* __restrict__ accum,
                                float* __restrict__ out) {
  if (threadIdx.x == 0 && blockIdx.x == 0) {
    float nv = accum[2];
    out[0] = accum[0] / nv;
    out[1] = accum[1] / nv;
  }
}

extern "C" void kernel_launch(void* const* d_in, const int* in_sizes, int n_in,
                              void* d_out, int out_size, void* d_ws, size_t ws_size,
                              hipStream_t stream) {
  const float* pf  = (const float*)d_in[0];
  const float* of  = (const float*)d_in[1];
  const float* e1i = (const float*)d_in[2];
  const float* e1j = (const float*)d_in[3];
  const float* e2j = (const float*)d_in[4];

  float* ws    = (float*)d_ws;
  float* accum = ws;  // [0]=loss_sum [1]=label_sum [2]=valid_sum
  hipMemsetAsync(accum, 0, 16 * sizeof(float), stream);

  const size_t pn_bytes = (size_t)BB * P * D * 2;
  const size_t on_bytes = (size_t)BB * O * D * 2;
  const size_t need = 64 + pn_bytes + on_bytes;

  if (ws_size >= need) {
    __hip_bfloat16* pn = (__hip_bfloat16*)((char*)d_ws + 64);
    __hip_bfloat16* on = (__hip_bfloat16*)((char*)d_ws + 64 + pn_bytes);
    prep_kernel<<<(BB * P + BB * O) / 4, 256, 0, stream>>>(pf, of, pn, on);
    icl_main2<<<BB * (P / 64), 256, 0, stream>>>(pn, on, e1i, e1j, e2j, accum);
  } else {
    float* invp = ws + 16;
    float* invo = ws + 16 + BB * P;
    norm_kernel<<<(BB * P + BB * O) / 4, 256, 0, stream>>>(pf, of, invp, invo);
    icl_main_v1<<<BB * (P / 128), 256, 0, stream>>>(pf, of, e1i, e1j, e2j, invp, invo, accum);
  }
  finalize_kernel<<<1, 64, 0, stream>>>(accum, (float*)d_out);
}